// Round 1
// 356.651 us; speedup vs baseline: 1.0039x; 1.0039x over previous
//
#include <hip/hip_runtime.h>
#include <stdint.h>

#define NB 2
#define NN 2048
#define MM 64
#define CC 256
#define HH 8
#define DD 32
#define PP 6
#define ATT_SCALE 0.17677669529663687f  // 1/sqrt(32)
#define NGEMMB 768                      // 3072 GEMM wave-tasks / 4 waves per block

typedef __attribute__((ext_vector_type(8))) short short8;
typedef __attribute__((ext_vector_type(4))) float f32x4;

__device__ __forceinline__ uint16_t f2bf(float f) {
  union { float f; uint32_t u; } c; c.f = f;
  return (uint16_t)((c.u + 0x7fffu + ((c.u >> 16) & 1u)) >> 16);  // RNE
}
__device__ __forceinline__ float blo(uint32_t u) {
  union { uint32_t u; float f; } c; c.u = u << 16; return c.f;
}
__device__ __forceinline__ float bhi(uint32_t u) {
  union { uint32_t u; float f; } c; c.u = u & 0xffff0000u; return c.f;
}

// ---------------------------------------------------------------------------
// One-shot f32 -> bf16 of cf (A matrix) and Wq|Wk|Wi|Wo (concatenated).
// Removes the per-block redundant in-register pack from all GEMMs.
// ---------------------------------------------------------------------------
__global__ __launch_bounds__(256) void k_prep(
    const float* __restrict__ cf,
    const float* __restrict__ Wq, const float* __restrict__ Wk,
    const float* __restrict__ Wi, const float* __restrict__ Wo,
    uint16_t* __restrict__ cfb, uint16_t* __restrict__ Wb) {
  const int tid = blockIdx.x * 256 + threadIdx.x;
  const int e0 = tid * 4;
  const int CFN = NB * NN * CC;  // 1048576
  const float* src;
  uint16_t* dst;
  if (e0 < CFN) {
    src = cf + e0; dst = cfb + e0;
  } else {
    const int w = e0 - CFN;
    const int which = w >> 16;    // 65536 elems per W
    const int off = w & 65535;
    if (which == 0) src = Wq + off;
    else if (which == 1) src = Wk + off;
    else if (which == 2) src = Wi + off;
    else src = Wo + off;
    dst = Wb + w;
  }
  const float4 x = *(const float4*)src;
  ushort4 o;
  o.x = f2bf(x.x); o.y = f2bf(x.y); o.z = f2bf(x.z); o.w = f2bf(x.w);
  *(ushort4*)dst = o;
}

// ---------------------------------------------------------------------------
// Combined dispatch: blocks [0,NGEMMB) do the QKV GEMM (4 single-wave tile
// tasks per 256-thread block, pre-converted bf16 inputs); blocks
// [NGEMMB, NGEMMB+B*N) do exact top-M selection for one (b,n) row (phase B of
// the old fused kernel) and write s_idx + gathered pg comps to workspace.
// The GEMM is independent of selection, so it hides under the pg stream.
// ---------------------------------------------------------------------------
__global__ __launch_bounds__(256) void k_select_qkv(
    const float* __restrict__ pg,
    const uint16_t* __restrict__ cfb, const uint16_t* __restrict__ Wb,
    const float* __restrict__ bq, const float* __restrict__ bk, const float* __restrict__ bi,
    float* __restrict__ Qo, uint16_t* __restrict__ Ko, uint16_t* __restrict__ Vo,
    int* __restrict__ idx_out, float* __restrict__ npg_out) {
  __shared__ float s_mn[4], s_mx[4];
  __shared__ uint32_t s_wsum[4];
  __shared__ uint32_t s_hist[256];
  __shared__ uint32_t s_scan[256];
  __shared__ float s_cd[NN];
  __shared__ uint16_t s_cj[NN];
  __shared__ int s_tbin;
  __shared__ uint32_t s_c0;
  __shared__ int s_cw;
  __shared__ int s_ct;
  __shared__ int s_idx[MM];

  if (blockIdx.x < NGEMMB) {
    // ---- QKV GEMM: task = (z, y, x); 16 rows x 64 cols per wave, K=256.
    const int task = blockIdx.x * 4 + (threadIdx.x >> 6);
    const int z = task >> 10;            // 0:Q 1:K 2:V(Wi)
    const int rem = task & 1023;
    const int row0 = (rem & 255) * 16;
    const int c0 = (rem >> 8) * 64;
    const uint16_t* W = Wb + (size_t)z * (CC * CC);
    const float* bias = (z == 0) ? bq : ((z == 1) ? bk : bi);
    const int lane = threadIdx.x & 63;
    const int m = lane & 15;
    const int quad = lane >> 4;

    f32x4 acc0 = {0.f, 0.f, 0.f, 0.f};
    f32x4 acc1 = {0.f, 0.f, 0.f, 0.f};
    f32x4 acc2 = {0.f, 0.f, 0.f, 0.f};
    f32x4 acc3 = {0.f, 0.f, 0.f, 0.f};
#pragma unroll
    for (int k0 = 0; k0 < CC; k0 += 32) {
      const short8 a  = *(const short8*)(cfb + (size_t)(row0 + m) * CC + k0 + quad * 8);
      const short8 f0 = *(const short8*)(W + (size_t)(c0 + 0 + m) * CC + k0 + quad * 8);
      const short8 f1 = *(const short8*)(W + (size_t)(c0 + 16 + m) * CC + k0 + quad * 8);
      const short8 f2 = *(const short8*)(W + (size_t)(c0 + 32 + m) * CC + k0 + quad * 8);
      const short8 f3 = *(const short8*)(W + (size_t)(c0 + 48 + m) * CC + k0 + quad * 8);
      acc0 = __builtin_amdgcn_mfma_f32_16x16x32_bf16(a, f0, acc0, 0, 0, 0);
      acc1 = __builtin_amdgcn_mfma_f32_16x16x32_bf16(a, f1, acc1, 0, 0, 0);
      acc2 = __builtin_amdgcn_mfma_f32_16x16x32_bf16(a, f2, acc2, 0, 0, 0);
      acc3 = __builtin_amdgcn_mfma_f32_16x16x32_bf16(a, f3, acc3, 0, 0, 0);
    }
    const int orow = row0 + quad * 4;
    f32x4 accs[4] = {acc0, acc1, acc2, acc3};
#pragma unroll
    for (int f = 0; f < 4; ++f) {
      const int col = c0 + f * 16 + m;
      const float bv = bias[col];
#pragma unroll
      for (int r = 0; r < 4; ++r) {
        const float val = accs[f][r] + bv;
        const size_t o = (size_t)(orow + r) * CC + col;
        if (z == 0) Qo[o] = val;
        else if (z == 1) Ko[o] = f2bf(val);
        else Vo[o] = f2bf(val);
      }
    }
    return;
  }

  // ---- exact top-M selection for one (b,n) row
  const int row = blockIdx.x - NGEMMB;  // b*N + n
  const int t = threadIdx.x;
  const int wave = t >> 6;
  const int lane = t & 63;

  if (t < MM) s_idx[t] = t;  // defensive default

  const float4* base = (const float4*)(pg + (size_t)row * NN * PP);

  float d[8];
  float mn = 3.4e38f, mx = -3.4e38f;
#pragma unroll
  for (int i = 0; i < 4; i++) {
    const int j0 = i * 512 + 2 * t;  // thread covers points j0, j0+1
    const float4 qa = base[(size_t)(j0 >> 1) * 3 + 0];
    const float4 qb = base[(size_t)(j0 >> 1) * 3 + 1];
    const float4 qc = base[(size_t)(j0 >> 1) * 3 + 2];
    float s0 = __fmul_rn(qa.x, qa.x);
    s0 = __fadd_rn(s0, __fmul_rn(qa.y, qa.y));
    s0 = __fadd_rn(s0, __fmul_rn(qa.z, qa.z));
    s0 = __fadd_rn(s0, __fmul_rn(qa.w, qa.w));
    s0 = __fadd_rn(s0, __fmul_rn(qb.x, qb.x));
    s0 = __fadd_rn(s0, __fmul_rn(qb.y, qb.y));
    float s1 = __fmul_rn(qb.z, qb.z);
    s1 = __fadd_rn(s1, __fmul_rn(qb.w, qb.w));
    s1 = __fadd_rn(s1, __fmul_rn(qc.x, qc.x));
    s1 = __fadd_rn(s1, __fmul_rn(qc.y, qc.y));
    s1 = __fadd_rn(s1, __fmul_rn(qc.z, qc.z));
    s1 = __fadd_rn(s1, __fmul_rn(qc.w, qc.w));
    const float d0 = __fsqrt_rn(s0);
    const float d1 = __fsqrt_rn(s1);
    d[2 * i] = d0; d[2 * i + 1] = d1;
    mn = fminf(mn, fminf(d0, d1));
    mx = fmaxf(mx, fmaxf(d0, d1));
  }

#pragma unroll
  for (int off = 32; off; off >>= 1) {
    mn = fminf(mn, __shfl_xor(mn, off));
    mx = fmaxf(mx, __shfl_xor(mx, off));
  }
  if (lane == 0) { s_mn[wave] = mn; s_mx[wave] = mx; }
  s_hist[t] = 0;
  __syncthreads();
  mn = fminf(fminf(s_mn[0], s_mn[1]), fminf(s_mn[2], s_mn[3]));
  mx = fmaxf(fmaxf(s_mx[0], s_mx[1]), fmaxf(s_mx[2], s_mx[3]));
  const float range = mx - mn;
  const float scale = (range > 0.f) ? (256.0f / range) : 0.f;

  int bins[8];
#pragma unroll
  for (int i = 0; i < 8; i++) {
    int bn = (int)((d[i] - mn) * scale);
    bn = (bn > 255) ? 255 : (bn < 0 ? 0 : bn);
    bins[i] = bn;
    atomicAdd(&s_hist[bn], 1u);
  }
  __syncthreads();

  // inclusive scan of 256 bins: wave shuffle scan + cross-wave combine
  {
    uint32_t x = s_hist[t];
#pragma unroll
    for (int off = 1; off < 64; off <<= 1) {
      const uint32_t y = __shfl_up(x, off);
      if (lane >= off) x += y;
    }
    if (lane == 63) s_wsum[wave] = x;
    __syncthreads();
    uint32_t pre = 0;
    for (int w = 0; w < wave; w++) pre += s_wsum[w];
    x += pre;
    s_scan[t] = x;
  }
  if (t == 0) { s_cw = 0; s_ct = 0; }
  __syncthreads();

  if (s_scan[t] >= (uint32_t)MM && (t == 0 || s_scan[t - 1] < (uint32_t)MM)) {
    s_tbin = t;
    s_c0 = (t == 0) ? 0u : s_scan[t - 1];
  }
  __syncthreads();

  const int tbin = s_tbin;
  const int c0 = (int)s_c0;

#pragma unroll
  for (int i = 0; i < 8; i++) {
    const int j = (i >> 1) * 512 + 2 * t + (i & 1);
    if (bins[i] < tbin) {
      const int pos = atomicAdd(&s_cw, 1);
      if (pos < MM) s_idx[pos] = j;
    } else if (bins[i] == tbin) {
      const int pos = atomicAdd(&s_ct, 1);
      s_cd[pos] = d[i];
      s_cj[pos] = (uint16_t)j;
    }
  }
  __syncthreads();

  // wave 0: exact (dist, index)-ordered pick of remaining r slots
  if (t < 64) {
    const int cnt = s_ct;
    const int r = MM - c0;
    for (int it = 0; it < r; ++it) {
      float bd = 3.4e38f; int bj = 0x7fffffff; int bi_ = -1;
      for (int i = t; i < cnt; i += 64) {
        const float dd = s_cd[i]; const int jj = (int)s_cj[i];
        if (dd < bd || (dd == bd && jj < bj)) { bd = dd; bj = jj; bi_ = i; }
      }
#pragma unroll
      for (int off = 32; off; off >>= 1) {
        const float od = __shfl_xor(bd, off);
        const int oj = __shfl_xor(bj, off);
        const int oi = __shfl_xor(bi_, off);
        if (od < bd || (od == bd && oj < bj)) { bd = od; bj = oj; bi_ = oi; }
      }
      if (t == 0 && bi_ >= 0) {
        s_cd[bi_] = 3.4e38f;
        s_idx[c0 + it] = bj;
      }
      __threadfence_block();
    }
  }
  __syncthreads();

  // write selected indices + gathered pg comps (row is L2/HBM; coalesced out)
  if (t < MM) {
    const int jj = s_idx[t] & (NN - 1);
    idx_out[(size_t)row * MM + t] = jj;
    const float2* p = (const float2*)(pg + ((size_t)row * NN + (size_t)jj) * PP);
    const float2 p0 = p[0], p1 = p[1], p2 = p[2];
    float2* np = (float2*)(npg_out + ((size_t)row * MM + t) * PP);
    np[0] = p0; np[1] = p1; np[2] = p2;
  }
}

// ---------------------------------------------------------------------------
// Attention per (b,n): folded e-term, gathered QK scores, wave softmax,
// gathered V sum. Small LDS -> thread-capped occupancy.
// ---------------------------------------------------------------------------
__global__ __launch_bounds__(256) void k_attn(
    const float* __restrict__ Q, const uint16_t* __restrict__ K,
    const uint16_t* __restrict__ V,
    const float* __restrict__ Wl, const float* __restrict__ bl,
    const float* __restrict__ u, const float* __restrict__ v,
    const int* __restrict__ idx_in, const float* __restrict__ npg_in,
    uint16_t* __restrict__ attnV) {
  const int row = blockIdx.x;  // b*N + n
  const int b = row >> 11;
  const int t = threadIdx.x;
  const int wave = t >> 6;
  const int lane = t & 63;

  __shared__ int s_idx[MM];
  __shared__ float s_npg[MM][7];
  __shared__ float s_qu[CC];
  __shared__ float s_wt[HH][8];
  __shared__ float s_sc[HH][MM];
  __shared__ float s_part[CC];

  const float qv_ = Q[(size_t)row * CC + t];
  s_qu[t] = qv_ + u[t];
  if (t < MM) {
    s_idx[t] = idx_in[(size_t)row * MM + t];
    const float2* np = (const float2*)(npg_in + ((size_t)row * MM + t) * PP);
    const float2 p0 = np[0], p1 = np[1], p2 = np[2];
    s_npg[t][0] = p0.x; s_npg[t][1] = p0.y;
    s_npg[t][2] = p1.x; s_npg[t][3] = p1.y;
    s_npg[t][4] = p2.x; s_npg[t][5] = p2.y;
  }

  {
    const int h = t >> 5;
    const float qpv = qv_ + v[t];
    float part[7];
#pragma unroll
    for (int p = 0; p < 6; p++) part[p] = Wl[(size_t)t * PP + p] * qpv;
    part[6] = bl[t] * qpv;
#pragma unroll
    for (int off = 1; off < 32; off <<= 1) {
#pragma unroll
      for (int p = 0; p < 7; p++) part[p] += __shfl_xor(part[p], off);
    }
    if ((t & 31) == 0) {
#pragma unroll
      for (int p = 0; p < 7; p++) s_wt[h][p] = part[p];
    }
  }
  __syncthreads();

  // scores: wave w handles h=w and h=w+4; m = lane. K is bf16.
#pragma unroll
  for (int pr = 0; pr < 2; ++pr) {
    const int h = wave + pr * 4;
    const int m = lane;
    const int kidx = s_idx[m] & (NN - 1);
    const uint4* kr = (const uint4*)(K + ((size_t)(b * NN + kidx)) * CC + h * DD);
    float acc = s_wt[h][6];
#pragma unroll
    for (int p = 0; p < 6; p++) acc += s_npg[m][p] * s_wt[h][p];
    const float* qu = &s_qu[h * DD];
    float a2 = 0.f;
#pragma unroll
    for (int w4 = 0; w4 < 4; w4++) {
      const uint4 kv = kr[w4];
      const float* q8 = qu + w4 * 8;
      a2 += q8[0] * blo(kv.x) + q8[1] * bhi(kv.x)
          + q8[2] * blo(kv.y) + q8[3] * bhi(kv.y)
          + q8[4] * blo(kv.z) + q8[5] * bhi(kv.z)
          + q8[6] * blo(kv.w) + q8[7] * bhi(kv.w);
    }
    s_sc[h][m] = (acc + a2) * ATT_SCALE;
  }
  __syncthreads();

  // softmax over m
#pragma unroll
  for (int pr = 0; pr < 2; ++pr) {
    const int h = wave + pr * 4;
    const float x = s_sc[h][lane];
    float mxv = x;
#pragma unroll
    for (int off = 32; off; off >>= 1) mxv = fmaxf(mxv, __shfl_xor(mxv, off));
    const float e = expf(x - mxv);
    float sm = e;
#pragma unroll
    for (int off = 32; off; off >>= 1) sm += __shfl_xor(sm, off);
    s_sc[h][lane] = e / sm;
  }
  __syncthreads();

  // weighted V sum (bf16 V, uint32 = 2 channels/lane, 2 m-halves)
  {
    const int h2 = t >> 7;
    const int ci = (t & 127) * 2;
    const int h = ci >> 5;
    const uint32_t* Vb32 = (const uint32_t*)(V + (size_t)b * NN * CC);
    float a0 = 0.f, a1 = 0.f;
#pragma unroll 8
    for (int m = h2; m < MM; m += 2) {
      const uint32_t pv = Vb32[(size_t)(s_idx[m] & (NN - 1)) * (CC / 2) + (ci >> 1)];
      const float p = s_sc[h][m];
      a0 += p * blo(pv);
      a1 += p * bhi(pv);
    }
    if (h2 == 1) { s_part[ci] = a0; s_part[ci + 1] = a1; }
    __syncthreads();
    if (h2 == 0) {
      attnV[(size_t)row * CC + ci]     = f2bf(a0 + s_part[ci]);
      attnV[(size_t)row * CC + ci + 1] = f2bf(a1 + s_part[ci + 1]);
    }
  }
}

// ---------------------------------------------------------------------------
// Output GEMM: A = attnV (bf16), W = pre-converted Wo (bf16).
// ---------------------------------------------------------------------------
__global__ __launch_bounds__(64) void k_gemm_out(const uint16_t* __restrict__ A,
                                                 const uint16_t* __restrict__ W,
                                                 const float* __restrict__ bias,
                                                 float* __restrict__ O) {
  const int lane = threadIdx.x;
  const int m = lane & 15;
  const int quad = lane >> 4;
  const int row0 = blockIdx.x * 16;
  const int c0 = blockIdx.y * 32;

  f32x4 acc0 = {0.f, 0.f, 0.f, 0.f};
  f32x4 acc1 = {0.f, 0.f, 0.f, 0.f};

#pragma unroll
  for (int k0 = 0; k0 < CC; k0 += 32) {
    const short8 a  = *(const short8*)(A + (size_t)(row0 + m) * CC + k0 + quad * 8);
    const short8 f0 = *(const short8*)(W + (size_t)(c0 + 0 + m) * CC + k0 + quad * 8);
    const short8 f1 = *(const short8*)(W + (size_t)(c0 + 16 + m) * CC + k0 + quad * 8);
    acc0 = __builtin_amdgcn_mfma_f32_16x16x32_bf16(a, f0, acc0, 0, 0, 0);
    acc1 = __builtin_amdgcn_mfma_f32_16x16x32_bf16(a, f1, acc1, 0, 0, 0);
  }

  const int orow = row0 + quad * 4;
  f32x4 accs[2] = {acc0, acc1};
#pragma unroll
  for (int f = 0; f < 2; ++f) {
    const int col = c0 + f * 16 + m;
    const float bv = bias[col];
#pragma unroll
    for (int r = 0; r < 4; ++r) {
      O[(size_t)(orow + r) * CC + col] = accs[f][r] + bv;
    }
  }
}

// ---------------------------------------------------------------------------
extern "C" void kernel_launch(void* const* d_in, const int* in_sizes, int n_in,
                              void* d_out, int out_size, void* d_ws, size_t ws_size,
                              hipStream_t stream) {
  const float* pg = (const float*)d_in[0];
  const float* cf = (const float*)d_in[1];
  // d_in[2] = mask (all true) — unused
  const float* Wq = (const float*)d_in[3];
  const float* bq = (const float*)d_in[4];
  const float* Wk = (const float*)d_in[5];
  const float* bk = (const float*)d_in[6];
  const float* Wl = (const float*)d_in[7];
  const float* bl = (const float*)d_in[8];
  const float* u  = (const float*)d_in[9];
  const float* v  = (const float*)d_in[10];
  const float* Wi = (const float*)d_in[11];
  const float* bi = (const float*)d_in[12];
  const float* Wo = (const float*)d_in[13];
  const float* bo = (const float*)d_in[14];

  char* ws = (char*)d_ws;
  float* Q      = (float*)ws;                                   // 4 MB (f32)
  uint16_t* K   = (uint16_t*)(ws + (size_t)4  * (1 << 20));     // 2 MB (bf16)
  uint16_t* V   = (uint16_t*)(ws + (size_t)6  * (1 << 20));     // 2 MB (bf16)
  uint16_t* aV  = (uint16_t*)(ws + (size_t)8  * (1 << 20));     // 2 MB (bf16)
  uint16_t* cfb = (uint16_t*)(ws + (size_t)10 * (1 << 20));     // 2 MB (bf16 cf)
  uint16_t* Wb  = (uint16_t*)(ws + (size_t)12 * (1 << 20));     // 512 KB (Wq|Wk|Wi|Wo bf16)
  int* idxb     = (int*)(ws + (size_t)12 * (1 << 20) + (512 << 10));   // 1 MB
  float* npgb   = (float*)(ws + (size_t)13 * (1 << 20) + (512 << 10)); // 6 MB
  float* out = (float*)d_out;

  // 1.31M f32 elems -> bf16, 4 per thread, 1280 blocks exact
  hipLaunchKernelGGL(k_prep, dim3(1280), dim3(256), 0, stream,
                     cf, Wq, Wk, Wi, Wo, cfb, Wb);
  hipLaunchKernelGGL(k_select_qkv, dim3(NGEMMB + NB * NN), dim3(256), 0, stream,
                     pg, cfb, Wb, bq, bk, bi, Q, K, V, idxb, npgb);
  hipLaunchKernelGGL(k_attn, dim3(NB * NN), dim3(256), 0, stream,
                     Q, K, V, Wl, bl, u, v, idxb, npgb, aV);
  hipLaunchKernelGGL(k_gemm_out, dim3(256, 8), dim3(64), 0, stream,
                     aV, Wb + (size_t)3 * CC * CC, bo, out);
}